// Round 5
// baseline (196.309 us; speedup 1.0000x reference)
//
#include <hip/hip_runtime.h>
#include <math.h>

#define NV 65536
#define NE 4096
#define NP 4096
#define NT 512
#define NGROUP 64          // point groups of 64 points
#define NQ 4               // edge quarters
#define EQ (NE / NQ)       // 1024 edges per quarter
#define SENTF 1000000000.0f
#define BIGF 1e30f

// ---------------- wave(64) reduction helpers ----------------
__device__ __forceinline__ float waveMinF(float v) {
    #pragma unroll
    for (int o = 32; o; o >>= 1) v = fminf(v, __shfl_xor(v, o, 64));
    return v;
}
__device__ __forceinline__ int waveMinI(int v) {
    #pragma unroll
    for (int o = 32; o; o >>= 1) v = min(v, __shfl_xor(v, o, 64));
    return v;
}

// ---------------- kernel 1: per-edge params + table repack + counter zero ----------------
__global__ void prep_kernel(const float* __restrict__ verts,
                            const int*   __restrict__ edges,
                            const float* __restrict__ tab,
                            float*  __restrict__ ea,  float*  __restrict__ eb,
                            float2* __restrict__ pk2, float4* __restrict__ pk4,
                            float4* __restrict__ tb4,
                            unsigned int* __restrict__ grpCnt,
                            unsigned int* __restrict__ gCnt) {
    int e = blockIdx.x * blockDim.x + threadIdx.x;
    if (blockIdx.x == 0) {
        if (threadIdx.x < NGROUP) grpCnt[threadIdx.x] = 0u;
        if (threadIdx.x == NGROUP) *gCnt = 0u;
    }
    if (e < NT) {
        const float* r = tab + 7 * e;
        tb4[e] = make_float4(r[3], r[4], r[5], r[6]);
    }
    if (e >= NE) return;
    int i0 = edges[2 * e + 0];
    int i1 = edges[2 * e + 1];
    float x0 = verts[3 * i0 + 0], y0 = verts[3 * i0 + 1];
    float x1 = verts[3 * i1 + 0], y1 = verts[3 * i1 + 1];
    float a = (y0 - y1) / (x0 - x1);
    float b = y0 - a * x0;
    ea[e] = a; eb[e] = b;
    pk2[e] = make_float2(fminf(x0, x1), fmaxf(x0, x1));
    pk4[e] = make_float4(fminf(y0, y1), fmaxf(y0, y1), 1.0f / a, b);  // reciprocal hoisted
}

// ---------------- kernel 2: fused transposed phase2 + combine + table + scan ----------------
// grid = 256 blocks (64 groups x 4 quarters), 1024 threads = 16 waves.
// Phase 2 transposed: lane = point (64 points/group), wave iterates 64 edges of
// its slice via LDS same-address broadcast.
__global__ __launch_bounds__(1024) void fused_kernel(
        const float*  __restrict__ verts,
        const int*    __restrict__ listAll,
        const float*  __restrict__ ea,  const float*  __restrict__ eb,
        const float2* __restrict__ pk2, const float4* __restrict__ pk4,
        const float4* __restrict__ tb4,
        float4* __restrict__ gP4, int* __restrict__ gPn,
        float* __restrict__ mArr, int* __restrict__ vArr,
        unsigned int* __restrict__ grpCnt, unsigned int* __restrict__ gCnt,
        float* __restrict__ out) {
    __shared__ float4 sE[EQ];              // 16 KB staged edge quarter
    __shared__ float  sStat[16][5][64];    // 20 KB per-wave partials
    __shared__ float  sCY[64], sPX[64], sL1[64];
    __shared__ unsigned int sTicket;
    __shared__ float  wAgg[16], wSum[16];  // scan scratch

    const int tid  = threadIdx.x;
    const int lane = tid & 63;
    const int w    = tid >> 6;          // wave 0..15
    const int g    = blockIdx.x >> 2;   // point group
    const int q    = blockIdx.x & 3;    // edge quarter
    const int pBase = g * 64;

    // issue staging load early
    float4 st = pk4[q * EQ + tid];

    // ---- phase 1 (per group, recomputed by each quarter-block): wave w -> 4 points ----
    #pragma unroll
    for (int pp = 0; pp < 4; ++pp) {
        int p  = pBase + w * 4 + pp;
        int vi = listAll[p];
        float px = verts[3 * vi + 0];
        float py = verts[3 * vi + 1];
        int minIdx = NE;
        for (int it = 0; it < NE / 64; ++it) {
            int e = it * 64 + lane;
            float2 qq = pk2[e];
            bool hit = (px > qq.x) && (px < qq.y);
            if (hit) minIdx = e;
            if (__any(hit)) break;
        }
        minIdx = waveMinI(minIdx);
        int idx = (minIdx >= NE) ? (NE - 1) : minIdx;
        float exposeY = ea[idx] * px + eb[idx];
        if (lane == 0) {
            sCY[w * 4 + pp] = 0.5f * (py + exposeY);
            sL1[w * 4 + pp] = fabsf(py - exposeY);
            sPX[w * 4 + pp] = px;
        }
    }

    sE[tid] = st;
    __syncthreads();

    const float cyl = sCY[lane];   // my point's cy
    const float cxl = sPX[lane];   // my point's cx (= px)

    // ---- phase 2 transposed: wave w covers edges [w*64, w*64+64) of this quarter ----
    int   nAcc = 0, hasS = 0, hasI = 0;
    float xallmx = -SENTF, xallmn = SENTF;
    float xs = SENTF, xinf = -SENTF;
    #pragma unroll 4
    for (int k = 0; k < 64; ++k) {
        float4 q4 = sE[w * 64 + k];          // same address across lanes -> broadcast
        bool  c  = (cyl > q4.x) && (cyl < q4.y);
        float xi = (cyl - q4.w) * q4.z;      // identical arithmetic to validated R2 path
        nAcc += c ? 1 : 0;
        xallmx = fmaxf(xallmx, c ? xi : -SENTF);
        xallmn = fminf(xallmn, c ? xi :  SENTF);
        bool sp  = c && (xi >= cxl);
        bool in_ = c && (xi <  cxl);
        xs   = fminf(xs,   sp  ? xi :  SENTF);
        xinf = fmaxf(xinf, in_ ? xi : -SENTF);
        hasS |= sp ? 1 : 0;
        hasI |= in_ ? 1 : 0;
    }
    sStat[w][0][lane] = xallmx;
    sStat[w][1][lane] = xallmn;
    sStat[w][2][lane] = xs;
    sStat[w][3][lane] = xinf;
    sStat[w][4][lane] = __int_as_float(nAcc | (hasS << 16) | (hasI << 24));
    __syncthreads();

    // ---- fold 16 waves' partials (waves 0..4, one stat each) ----
    if (tid < 320) {
        int s = tid >> 6, l = tid & 63;   // s uniform per wave
        if (s == 0) {
            float a0 = sStat[0][0][l];
            #pragma unroll
            for (int ww = 1; ww < 16; ++ww) a0 = fmaxf(a0, sStat[ww][0][l]);
            sStat[0][0][l] = a0;
        } else if (s == 1) {
            float a0 = sStat[0][1][l];
            #pragma unroll
            for (int ww = 1; ww < 16; ++ww) a0 = fminf(a0, sStat[ww][1][l]);
            sStat[0][1][l] = a0;
        } else if (s == 2) {
            float a0 = sStat[0][2][l];
            #pragma unroll
            for (int ww = 1; ww < 16; ++ww) a0 = fminf(a0, sStat[ww][2][l]);
            sStat[0][2][l] = a0;
        } else if (s == 3) {
            float a0 = sStat[0][3][l];
            #pragma unroll
            for (int ww = 1; ww < 16; ++ww) a0 = fmaxf(a0, sStat[ww][3][l]);
            sStat[0][3][l] = a0;
        } else {
            int a0 = __float_as_int(sStat[0][4][l]);
            #pragma unroll
            for (int ww = 1; ww < 16; ++ww) a0 += __float_as_int(sStat[ww][4][l]);
            sStat[0][4][l] = __int_as_float(a0);
        }
    }
    __syncthreads();

    // ---- write quarter partials ----
    if (tid < 64) {
        float4 o;
        o.x = sStat[0][0][tid]; o.y = sStat[0][1][tid];
        o.z = sStat[0][2][tid]; o.w = sStat[0][3][tid];
        gP4[q * NP + pBase + tid] = o;
        gPn[q * NP + pBase + tid] = __float_as_int(sStat[0][4][tid]);
    }

    // ---- group ticket: 4th block of this group does combine + table ----
    __threadfence();
    __syncthreads();
    if (tid == 0)
        sTicket = __hip_atomic_fetch_add(&grpCnt[g], 1u, __ATOMIC_ACQ_REL, __HIP_MEMORY_SCOPE_AGENT);
    __syncthreads();
    if (sTicket != NQ - 1) return;
    __threadfence();   // acquire side: discard stale L1 before reading peers' partials

    // ---- combine quarters + table min: wave w -> 4 points ----
    #pragma unroll
    for (int pp = 0; pp < 4; ++pp) {
        int pl = w * 4 + pp;
        int p  = pBase + pl;
        float4 f4 = gP4[(lane & 3) * NP + p];
        int    pn = gPn[(lane & 3) * NP + p];
        #pragma unroll
        for (int o = 1; o <= 2; o <<= 1) {
            float tx = __shfl_xor(f4.x, o, 64);
            float ty = __shfl_xor(f4.y, o, 64);
            float tz = __shfl_xor(f4.z, o, 64);
            float tw = __shfl_xor(f4.w, o, 64);
            int   tn = __shfl_xor(pn,  o, 64);
            f4.x = fmaxf(f4.x, tx);   // xallmx
            f4.y = fminf(f4.y, ty);   // xallmn
            f4.z = fminf(f4.z, tz);   // xs
            f4.w = fmaxf(f4.w, tw);   // xinf
            pn  += tn;
        }
        int n    = pn & 0xFFFF;
        int hS   = (pn >> 16) & 0xFF;
        int hI   = (pn >> 24) & 0xFF;
        bool valid = (n == 2) || ((n > 2) && (hS > 0) && (hI > 0));
        float dx  = (n == 2) ? (f4.x - f4.y) : (f4.z - f4.w);
        float L2v = fabsf(dx);
        float cy  = sCY[pl], L1v = sL1[pl], px = sPX[pl];
        float d1  = fabsf(cy - 1.0f);
        float d2  = fabsf(px - 1.0f);

        float pm = INFINITY;
        #pragma unroll
        for (int kk = 0; kk < NT / 64; ++kk) {
            float4 r = tb4[kk * 64 + lane];
            float al = fabsf(L1v - r.x) + fabsf(L2v - r.y) +
                       fabsf(d1 - r.z) + fabsf(d2 - r.w);
            pm = fminf(pm, al);
        }
        pm = waveMinF(pm);
        if (lane == 0) {
            mArr[p] = valid ? pm : BIGF;
            vArr[p] = valid ? 1 : 0;
        }
    }

    // ---- global ticket: last combine block does the scan ----
    __threadfence();
    __syncthreads();
    if (tid == 0)
        sTicket = __hip_atomic_fetch_add(gCnt, 1u, __ATOMIC_ACQ_REL, __HIP_MEMORY_SCOPE_AGENT);
    __syncthreads();
    if (sTicket != NGROUP - 1) return;
    __threadfence();   // acquire: all mArr/vArr visible

    // ---- cummin + masked sum (validated R2 scan body) ----
    {
        int t = tid;
        int l = t & 63, wd = t >> 6;
        float v[4]; int vl[4];
        #pragma unroll
        for (int j = 0; j < 4; j++) { v[j] = mArr[4 * t + j]; vl[j] = vArr[4 * t + j]; }
        float cmin = fminf(fminf(v[0], v[1]), fminf(v[2], v[3]));

        float inc = cmin;
        #pragma unroll
        for (int o = 1; o < 64; o <<= 1) {
            float u = __shfl_up(inc, o, 64);
            if (l >= o) inc = fminf(inc, u);
        }
        if (l == 63) wAgg[wd] = inc;
        __syncthreads();

        float wavePrefix = INFINITY;
        for (int i = 0; i < wd; i++) wavePrefix = fminf(wavePrefix, wAgg[i]);
        float excl = __shfl_up(inc, 1, 64);
        if (l == 0) excl = INFINITY;
        float run = fminf(wavePrefix, excl);

        float sum = 0.0f;
        #pragma unroll
        for (int j = 0; j < 4; j++) {
            run = fminf(run, v[j]);
            if (vl[j]) sum += run;
        }
        #pragma unroll
        for (int o = 32; o; o >>= 1) sum += __shfl_xor(sum, o, 64);
        if (l == 0) wSum[wd] = sum;
        __syncthreads();
        if (t == 0) {
            float s = 0.0f;
            for (int i = 0; i < 16; i++) s += wSum[i];
            out[0] = s;
        }
    }
}

extern "C" void kernel_launch(void* const* d_in, const int* in_sizes, int n_in,
                              void* d_out, int out_size, void* d_ws, size_t ws_size,
                              hipStream_t stream) {
    const float* verts   = (const float*)d_in[0];
    const float* tab     = (const float*)d_in[1];
    const int*   edges   = (const int*)d_in[2];
    const int*   listAll = (const int*)d_in[3];

    char* ws = (char*)d_ws;
    float4* pk4 = (float4*)ws;                    ws += NE * sizeof(float4);
    float4* tb4 = (float4*)ws;                    ws += NT * sizeof(float4);
    float4* gP4 = (float4*)ws;                    ws += NQ * NP * sizeof(float4);
    float2* pk2 = (float2*)ws;                    ws += NE * sizeof(float2);
    float*  ea  = (float*)ws;                     ws += NE * sizeof(float);
    float*  eb  = (float*)ws;                     ws += NE * sizeof(float);
    int*    gPn = (int*)ws;                       ws += NQ * NP * sizeof(int);
    float*  mArr= (float*)ws;                     ws += NP * sizeof(float);
    int*    vArr= (int*)ws;                       ws += NP * sizeof(int);
    unsigned int* grpCnt = (unsigned int*)ws;     ws += NGROUP * sizeof(unsigned int);
    unsigned int* gCnt   = (unsigned int*)ws;

    prep_kernel<<<(NE + 255) / 256, 256, 0, stream>>>(verts, edges, tab,
                                                      ea, eb, pk2, pk4, tb4,
                                                      grpCnt, gCnt);
    fused_kernel<<<NGROUP * NQ, 1024, 0, stream>>>(verts, listAll,
                                                   ea, eb, pk2, pk4, tb4,
                                                   gP4, gPn, mArr, vArr,
                                                   grpCnt, gCnt, (float*)d_out);
}

// Round 6
// 37.814 us; speedup vs baseline: 5.1915x; 5.1915x over previous
//
#include <hip/hip_runtime.h>
#include <math.h>

#define NV 65536
#define NE 4096
#define NP 4096
#define NT 512
#define NGROUP 64          // point groups of 64 points
#define NQ 4               // edge quarters
#define EQ (NE / NQ)       // 1024 edges per quarter
#define SENTF 1000000000.0f
#define BIGF 1e30f

// ---------------- wave(64) reduction helpers ----------------
__device__ __forceinline__ float waveMinF(float v) {
    #pragma unroll
    for (int o = 32; o; o >>= 1) v = fminf(v, __shfl_xor(v, o, 64));
    return v;
}
__device__ __forceinline__ int waveMinI(int v) {
    #pragma unroll
    for (int o = 32; o; o >>= 1) v = min(v, __shfl_xor(v, o, 64));
    return v;
}

// ---------------- kernel 1: per-edge params + table repack ----------------
__global__ void prep_kernel(const float* __restrict__ verts,
                            const int*   __restrict__ edges,
                            const float* __restrict__ tab,
                            float*  __restrict__ ea,  float*  __restrict__ eb,
                            float2* __restrict__ pk2, float4* __restrict__ pk4,
                            float4* __restrict__ tb4) {
    int e = blockIdx.x * blockDim.x + threadIdx.x;
    if (e < NT) {
        const float* r = tab + 7 * e;
        tb4[e] = make_float4(r[3], r[4], r[5], r[6]);
    }
    if (e >= NE) return;
    int i0 = edges[2 * e + 0];
    int i1 = edges[2 * e + 1];
    float x0 = verts[3 * i0 + 0], y0 = verts[3 * i0 + 1];
    float x1 = verts[3 * i1 + 0], y1 = verts[3 * i1 + 1];
    float a = (y0 - y1) / (x0 - x1);
    float b = y0 - a * x0;
    ea[e] = a; eb[e] = b;
    pk2[e] = make_float2(fminf(x0, x1), fmaxf(x0, x1));
    pk4[e] = make_float4(fminf(y0, y1), fmaxf(y0, y1), 1.0f / a, b);  // reciprocal hoisted
}

// ---------------- kernel 2: transposed phase2 partials ----------------
// grid = 256 blocks (64 groups x 4 quarters), 1024 threads = 16 waves.
// lane = point (64 points/group); wave w covers 64 edges of this quarter via
// LDS same-address broadcast. No fences, no atomics — kernel boundary orders.
__global__ __launch_bounds__(1024) void partial_kernel(
        const float*  __restrict__ verts,
        const int*    __restrict__ listAll,
        const float*  __restrict__ ea,  const float*  __restrict__ eb,
        const float2* __restrict__ pk2, const float4* __restrict__ pk4,
        float4* __restrict__ gP4, int* __restrict__ gPn,
        float* __restrict__ cyArr, float* __restrict__ l1Arr,
        float* __restrict__ pxArr) {
    __shared__ float4 sE[EQ];              // 16 KB staged edge quarter
    __shared__ float  sStat[16][5][64];    // 20 KB per-wave partials
    __shared__ float  sCY[64], sPX[64], sL1[64];

    const int tid  = threadIdx.x;
    const int lane = tid & 63;
    const int w    = tid >> 6;          // wave 0..15
    const int g    = blockIdx.x >> 2;   // point group
    const int q    = blockIdx.x & 3;    // edge quarter
    const int pBase = g * 64;

    // issue staging load early
    float4 st = pk4[q * EQ + tid];

    // ---- phase 1 (recomputed per quarter-block): wave w -> 4 points ----
    #pragma unroll
    for (int pp = 0; pp < 4; ++pp) {
        int p  = pBase + w * 4 + pp;
        int vi = listAll[p];
        float px = verts[3 * vi + 0];
        float py = verts[3 * vi + 1];
        int minIdx = NE;
        for (int it = 0; it < NE / 64; ++it) {
            int e = it * 64 + lane;
            float2 qq = pk2[e];
            bool hit = (px > qq.x) && (px < qq.y);
            if (hit) minIdx = e;
            if (__any(hit)) break;
        }
        minIdx = waveMinI(minIdx);
        int idx = (minIdx >= NE) ? (NE - 1) : minIdx;
        float exposeY = ea[idx] * px + eb[idx];
        if (lane == 0) {
            sCY[w * 4 + pp] = 0.5f * (py + exposeY);
            sL1[w * 4 + pp] = fabsf(py - exposeY);
            sPX[w * 4 + pp] = px;
        }
    }

    sE[tid] = st;
    __syncthreads();

    const float cyl = sCY[lane];   // my point's cy
    const float cxl = sPX[lane];   // my point's cx (= px)

    // ---- phase 2 transposed: wave w covers edges [w*64, w*64+64) of quarter ----
    int   nAcc = 0, hasS = 0, hasI = 0;
    float xallmx = -SENTF, xallmn = SENTF;
    float xs = SENTF, xinf = -SENTF;
    #pragma unroll 4
    for (int k = 0; k < 64; ++k) {
        float4 q4 = sE[w * 64 + k];          // same address across lanes -> broadcast
        bool  c  = (cyl > q4.x) && (cyl < q4.y);
        float xi = (cyl - q4.w) * q4.z;      // identical arithmetic to validated path
        nAcc += c ? 1 : 0;
        xallmx = fmaxf(xallmx, c ? xi : -SENTF);
        xallmn = fminf(xallmn, c ? xi :  SENTF);
        bool sp  = c && (xi >= cxl);
        bool in_ = c && (xi <  cxl);
        xs   = fminf(xs,   sp  ? xi :  SENTF);
        xinf = fmaxf(xinf, in_ ? xi : -SENTF);
        hasS |= sp ? 1 : 0;
        hasI |= in_ ? 1 : 0;
    }
    sStat[w][0][lane] = xallmx;
    sStat[w][1][lane] = xallmn;
    sStat[w][2][lane] = xs;
    sStat[w][3][lane] = xinf;
    sStat[w][4][lane] = __int_as_float(nAcc | (hasS << 16) | (hasI << 24));
    __syncthreads();

    // ---- fold 16 waves' partials (waves 0..4, one stat each) ----
    if (tid < 320) {
        int s = tid >> 6, l = tid & 63;
        if (s == 0) {
            float a0 = sStat[0][0][l];
            #pragma unroll
            for (int ww = 1; ww < 16; ++ww) a0 = fmaxf(a0, sStat[ww][0][l]);
            sStat[0][0][l] = a0;
        } else if (s == 1) {
            float a0 = sStat[0][1][l];
            #pragma unroll
            for (int ww = 1; ww < 16; ++ww) a0 = fminf(a0, sStat[ww][1][l]);
            sStat[0][1][l] = a0;
        } else if (s == 2) {
            float a0 = sStat[0][2][l];
            #pragma unroll
            for (int ww = 1; ww < 16; ++ww) a0 = fminf(a0, sStat[ww][2][l]);
            sStat[0][2][l] = a0;
        } else if (s == 3) {
            float a0 = sStat[0][3][l];
            #pragma unroll
            for (int ww = 1; ww < 16; ++ww) a0 = fmaxf(a0, sStat[ww][3][l]);
            sStat[0][3][l] = a0;
        } else {
            int a0 = __float_as_int(sStat[0][4][l]);
            #pragma unroll
            for (int ww = 1; ww < 16; ++ww) a0 += __float_as_int(sStat[ww][4][l]);
            sStat[0][4][l] = __int_as_float(a0);
        }
    }
    __syncthreads();

    // ---- write quarter partials, layout [g][q][64] for coalesced combine ----
    if (tid < 64) {
        float4 o;
        o.x = sStat[0][0][tid]; o.y = sStat[0][1][tid];
        o.z = sStat[0][2][tid]; o.w = sStat[0][3][tid];
        gP4[(g * NQ + q) * 64 + tid] = o;
        gPn[(g * NQ + q) * 64 + tid] = __float_as_int(sStat[0][4][tid]);
        if (q == 0) {
            cyArr[pBase + tid] = sCY[tid];
            l1Arr[pBase + tid] = sL1[tid];
            pxArr[pBase + tid] = sPX[tid];
        }
    }
}

// ---------------- kernel 3: combine quarters + table min ----------------
// grid = 64 blocks (one group each), 1024 threads = 16 waves, wave -> 4 points.
__global__ __launch_bounds__(1024) void combine_kernel(
        const float4* __restrict__ gP4, const int* __restrict__ gPn,
        const float*  __restrict__ cyArr, const float* __restrict__ l1Arr,
        const float*  __restrict__ pxArr, const float4* __restrict__ tb4,
        float* __restrict__ mArr, int* __restrict__ vArr) {
    const int tid  = threadIdx.x;
    const int lane = tid & 63;
    const int w    = tid >> 6;
    const int g    = blockIdx.x;
    const int pBase = g * 64;

    #pragma unroll
    for (int pp = 0; pp < 4; ++pp) {
        int pl = w * 4 + pp;
        int p  = pBase + pl;
        float4 f4 = gP4[(g * NQ + (lane & 3)) * 64 + pl];
        int    pn = gPn[(g * NQ + (lane & 3)) * 64 + pl];
        #pragma unroll
        for (int o = 1; o <= 2; o <<= 1) {
            float tx = __shfl_xor(f4.x, o, 64);
            float ty = __shfl_xor(f4.y, o, 64);
            float tz = __shfl_xor(f4.z, o, 64);
            float tw = __shfl_xor(f4.w, o, 64);
            int   tn = __shfl_xor(pn,  o, 64);
            f4.x = fmaxf(f4.x, tx);   // xallmx
            f4.y = fminf(f4.y, ty);   // xallmn
            f4.z = fminf(f4.z, tz);   // xs
            f4.w = fmaxf(f4.w, tw);   // xinf
            pn  += tn;
        }
        int n    = pn & 0xFFFF;
        int hS   = (pn >> 16) & 0xFF;
        int hI   = (pn >> 24) & 0xFF;
        bool valid = (n == 2) || ((n > 2) && (hS > 0) && (hI > 0));
        float dx  = (n == 2) ? (f4.x - f4.y) : (f4.z - f4.w);
        float L2v = fabsf(dx);
        float cy  = cyArr[p], L1v = l1Arr[p], px = pxArr[p];
        float d1  = fabsf(cy - 1.0f);
        float d2  = fabsf(px - 1.0f);

        float pm = INFINITY;
        #pragma unroll
        for (int kk = 0; kk < NT / 64; ++kk) {
            float4 r = tb4[kk * 64 + lane];
            float al = fabsf(L1v - r.x) + fabsf(L2v - r.y) +
                       fabsf(d1 - r.z) + fabsf(d2 - r.w);
            pm = fminf(pm, al);
        }
        pm = waveMinF(pm);
        if (lane == 0) {
            mArr[p] = valid ? pm : BIGF;
            vArr[p] = valid ? 1 : 0;
        }
    }
}

// ---------------- kernel 4: cummin + masked sum (single block) ----------------
__global__ __launch_bounds__(1024) void scan_kernel(const float* __restrict__ m,
                                                    const int*   __restrict__ valid,
                                                    float* __restrict__ out) {
    __shared__ float wAgg[16];
    __shared__ float wSum[16];
    int t = threadIdx.x;
    int lane = t & 63, wid = t >> 6;

    float v[4]; int vl[4];
    #pragma unroll
    for (int j = 0; j < 4; j++) { v[j] = m[4 * t + j]; vl[j] = valid[4 * t + j]; }
    float cmin = fminf(fminf(v[0], v[1]), fminf(v[2], v[3]));

    float inc = cmin;
    #pragma unroll
    for (int o = 1; o < 64; o <<= 1) {
        float u = __shfl_up(inc, o, 64);
        if (lane >= o) inc = fminf(inc, u);
    }
    if (lane == 63) wAgg[wid] = inc;
    __syncthreads();

    float wavePrefix = INFINITY;
    for (int i = 0; i < wid; i++) wavePrefix = fminf(wavePrefix, wAgg[i]);
    float excl = __shfl_up(inc, 1, 64);
    if (lane == 0) excl = INFINITY;
    float run = fminf(wavePrefix, excl);

    float sum = 0.0f;
    #pragma unroll
    for (int j = 0; j < 4; j++) {
        run = fminf(run, v[j]);
        if (vl[j]) sum += run;
    }
    #pragma unroll
    for (int o = 32; o; o >>= 1) sum += __shfl_xor(sum, o, 64);
    if (lane == 0) wSum[wid] = sum;
    __syncthreads();
    if (t == 0) {
        float s = 0.0f;
        for (int i = 0; i < 16; i++) s += wSum[i];
        out[0] = s;
    }
}

extern "C" void kernel_launch(void* const* d_in, const int* in_sizes, int n_in,
                              void* d_out, int out_size, void* d_ws, size_t ws_size,
                              hipStream_t stream) {
    const float* verts   = (const float*)d_in[0];
    const float* tab     = (const float*)d_in[1];
    const int*   edges   = (const int*)d_in[2];
    const int*   listAll = (const int*)d_in[3];

    char* ws = (char*)d_ws;
    float4* pk4 = (float4*)ws;                    ws += NE * sizeof(float4);
    float4* tb4 = (float4*)ws;                    ws += NT * sizeof(float4);
    float4* gP4 = (float4*)ws;                    ws += NQ * NP * sizeof(float4);
    float2* pk2 = (float2*)ws;                    ws += NE * sizeof(float2);
    float*  ea  = (float*)ws;                     ws += NE * sizeof(float);
    float*  eb  = (float*)ws;                     ws += NE * sizeof(float);
    int*    gPn = (int*)ws;                       ws += NQ * NP * sizeof(int);
    float*  cyArr = (float*)ws;                   ws += NP * sizeof(float);
    float*  l1Arr = (float*)ws;                   ws += NP * sizeof(float);
    float*  pxArr = (float*)ws;                   ws += NP * sizeof(float);
    float*  mArr= (float*)ws;                     ws += NP * sizeof(float);
    int*    vArr= (int*)ws;

    prep_kernel<<<(NE + 255) / 256, 256, 0, stream>>>(verts, edges, tab,
                                                      ea, eb, pk2, pk4, tb4);
    partial_kernel<<<NGROUP * NQ, 1024, 0, stream>>>(verts, listAll,
                                                     ea, eb, pk2, pk4,
                                                     gP4, gPn, cyArr, l1Arr, pxArr);
    combine_kernel<<<NGROUP, 1024, 0, stream>>>(gP4, gPn, cyArr, l1Arr, pxArr,
                                                tb4, mArr, vArr);
    scan_kernel<<<1, 1024, 0, stream>>>(mArr, vArr, (float*)d_out);
}

// Round 7
// 29.369 us; speedup vs baseline: 6.6843x; 1.2875x over previous
//
#include <hip/hip_runtime.h>
#include <math.h>

#define NV 65536
#define NE 4096
#define NP 4096
#define NT 512
#define NPB 16             // points per block
#define EW  256            // edges per wave (16 waves x 256 = 4096)
#define SENTF 1000000000.0f
#define BIGF 1e30f

// ---------------- wave(64) reduction helpers ----------------
__device__ __forceinline__ float waveMinF(float v) {
    #pragma unroll
    for (int o = 32; o; o >>= 1) v = fminf(v, __shfl_xor(v, o, 64));
    return v;
}
__device__ __forceinline__ int waveMinI(int v) {
    #pragma unroll
    for (int o = 32; o; o >>= 1) v = min(v, __shfl_xor(v, o, 64));
    return v;
}

// ---------------- kernel 1: per-edge params + table repack ----------------
__global__ void prep_kernel(const float* __restrict__ verts,
                            const int*   __restrict__ edges,
                            const float* __restrict__ tab,
                            float*  __restrict__ ea,  float*  __restrict__ eb,
                            float2* __restrict__ pk2, float4* __restrict__ pk4,
                            float4* __restrict__ tb4) {
    int e = blockIdx.x * blockDim.x + threadIdx.x;
    if (e < NT) {
        const float* r = tab + 7 * e;
        tb4[e] = make_float4(r[3], r[4], r[5], r[6]);
    }
    if (e >= NE) return;
    int i0 = edges[2 * e + 0];
    int i1 = edges[2 * e + 1];
    float x0 = verts[3 * i0 + 0], y0 = verts[3 * i0 + 1];
    float x1 = verts[3 * i1 + 0], y1 = verts[3 * i1 + 1];
    float a = (y0 - y1) / (x0 - x1);
    float b = y0 - a * x0;
    ea[e] = a; eb[e] = b;
    pk2[e] = make_float2(fminf(x0, x1), fmaxf(x0, x1));
    pk4[e] = make_float4(fminf(y0, y1), fmaxf(y0, y1), 1.0f / a, b);  // reciprocal hoisted
}

// ---------------- kernel 2: 256 blocks x 16 points, LDS-broadcast phase 2 ----------------
// block = 1024 threads = 16 waves. All 4096 edges staged in LDS (64 KB).
// Phase 1: wave w -> point w (early-exit first-hit search).
// Phase 2: lane = p*4 + s : point p in 0..15, edge-stream s in 0..3.
//          Wave w covers edges [w*256, (w+1)*256); iter k reads 4 distinct
//          float4s, each broadcast to 16 lanes (64 B per wave-instr).
__global__ __launch_bounds__(1024) void point_kernel(
        const float*  __restrict__ verts,
        const int*    __restrict__ listAll,
        const float*  __restrict__ ea,  const float*  __restrict__ eb,
        const float2* __restrict__ pk2, const float4* __restrict__ pk4,
        const float4* __restrict__ tb4,
        float* __restrict__ mOut, int* __restrict__ vOut) {
    __shared__ float4 sE[NE];              // 64 KB edge params (ymn, ymx, 1/a, b)
    __shared__ float  sW[16][NPB][5];      // per-wave folded stats (5 KB)
    __shared__ float  sF[NPB][5];          // cross-wave folded stats
    __shared__ float  sCY[NPB], sPX[NPB], sL1[NPB], sL2[NPB];
    __shared__ int    sVal[NPB];

    const int tid  = threadIdx.x;
    const int lane = tid & 63;
    const int w    = tid >> 6;          // wave 0..15
    const int pBase = blockIdx.x * NPB;

    // issue staging loads early (latency hides under phase 1)
    float4 r0 = pk4[tid];
    float4 r1 = pk4[1024 + tid];
    float4 r2 = pk4[2048 + tid];
    float4 r3 = pk4[3072 + tid];

    // ---- phase 1: wave w handles point w (validated early-exit search) ----
    {
        int p  = pBase + w;
        int vi = listAll[p];
        float px = verts[3 * vi + 0];
        float py = verts[3 * vi + 1];
        int minIdx = NE;
        for (int it = 0; it < NE / 64; ++it) {
            int e = it * 64 + lane;
            float2 q = pk2[e];
            bool hit = (px > q.x) && (px < q.y);
            if (hit) minIdx = e;
            if (__any(hit)) break;
        }
        minIdx = waveMinI(minIdx);
        int idx = (minIdx >= NE) ? (NE - 1) : minIdx;
        float exposeY = ea[idx] * px + eb[idx];
        if (lane == 0) {
            sCY[w] = 0.5f * (py + exposeY);
            sL1[w] = fabsf(py - exposeY);
            sPX[w] = px;
        }
    }

    sE[tid]        = r0;
    sE[1024 + tid] = r1;
    sE[2048 + tid] = r2;
    sE[3072 + tid] = r3;
    __syncthreads();

    // ---- phase 2: lane = p*4 + s ----
    const int   pl  = lane >> 2;        // my point 0..15
    const int   s   = lane & 3;         // my edge stream 0..3
    const float cyl = sCY[pl];
    const float cxl = sPX[pl];

    int   nAcc = 0, hasS = 0, hasI = 0;
    float xallmx = -SENTF, xallmn = SENTF;
    float xs = SENTF, xinf = -SENTF;
    #pragma unroll 8
    for (int k = 0; k < EW / 4; ++k) {                 // 64 iters
        float4 q4 = sE[w * EW + k * 4 + s];            // 4 distinct addrs/wave, 16-lane broadcast
        bool  c  = (cyl > q4.x) && (cyl < q4.y);
        float xi = (cyl - q4.w) * q4.z;                // identical arithmetic to validated path
        nAcc += c ? 1 : 0;
        xallmx = fmaxf(xallmx, c ? xi : -SENTF);
        xallmn = fminf(xallmn, c ? xi :  SENTF);
        bool sp  = c && (xi >= cxl);
        bool in_ = c && (xi <  cxl);
        xs   = fminf(xs,   sp  ? xi :  SENTF);
        xinf = fmaxf(xinf, in_ ? xi : -SENTF);
        hasS |= sp ? 1 : 0;
        hasI |= in_ ? 1 : 0;
    }

    // ---- fold the 4 streams of each point (xor within nibble) ----
    int packed = nAcc | (hasS << 16) | (hasI << 24);
    #pragma unroll
    for (int o = 1; o <= 2; o <<= 1) {
        xallmx = fmaxf(xallmx, __shfl_xor(xallmx, o, 64));
        xallmn = fminf(xallmn, __shfl_xor(xallmn, o, 64));
        xs     = fminf(xs,     __shfl_xor(xs,     o, 64));
        xinf   = fmaxf(xinf,   __shfl_xor(xinf,   o, 64));
        packed += __shfl_xor(packed, o, 64);
    }
    if (s == 0) {
        sW[w][pl][0] = xallmx;
        sW[w][pl][1] = xallmn;
        sW[w][pl][2] = xs;
        sW[w][pl][3] = xinf;
        sW[w][pl][4] = __int_as_float(packed);
    }
    __syncthreads();

    // ---- fold across 16 waves: 80 threads, one (point, stat) each ----
    if (tid < 80) {
        int pp = tid & 15, st = tid >> 4;
        if (st == 0) {
            float a0 = sW[0][pp][0];
            #pragma unroll
            for (int ww = 1; ww < 16; ++ww) a0 = fmaxf(a0, sW[ww][pp][0]);
            sF[pp][0] = a0;
        } else if (st == 1) {
            float a0 = sW[0][pp][1];
            #pragma unroll
            for (int ww = 1; ww < 16; ++ww) a0 = fminf(a0, sW[ww][pp][1]);
            sF[pp][1] = a0;
        } else if (st == 2) {
            float a0 = sW[0][pp][2];
            #pragma unroll
            for (int ww = 1; ww < 16; ++ww) a0 = fminf(a0, sW[ww][pp][2]);
            sF[pp][2] = a0;
        } else if (st == 3) {
            float a0 = sW[0][pp][3];
            #pragma unroll
            for (int ww = 1; ww < 16; ++ww) a0 = fmaxf(a0, sW[ww][pp][3]);
            sF[pp][3] = a0;
        } else {
            int a0 = __float_as_int(sW[0][pp][4]);
            #pragma unroll
            for (int ww = 1; ww < 16; ++ww) a0 += __float_as_int(sW[ww][pp][4]);
            sF[pp][4] = __int_as_float(a0);
        }
    }
    __syncthreads();

    // ---- per-point finish: valid, L2 ----
    if (tid < NPB) {
        int pn = __float_as_int(sF[tid][4]);
        int n  = pn & 0xFFFF;
        int hS = (pn >> 16) & 0xFF;
        int hI = (pn >> 24) & 0xFF;
        bool valid = (n == 2) || ((n > 2) && (hS > 0) && (hI > 0));
        float dx = (n == 2) ? (sF[tid][0] - sF[tid][1]) : (sF[tid][2] - sF[tid][3]);
        sL2[tid]  = fabsf(dx);
        sVal[tid] = valid ? 1 : 0;
    }
    __syncthreads();

    // ---- table min: wave w -> point w ----
    {
        float L1v = sL1[w], L2v = sL2[w];
        float d1  = fabsf(sCY[w] - 1.0f);
        float d2  = fabsf(sPX[w] - 1.0f);
        float pm = INFINITY;
        #pragma unroll
        for (int kk = 0; kk < NT / 64; ++kk) {
            float4 r = tb4[kk * 64 + lane];
            float al = fabsf(L1v - r.x) + fabsf(L2v - r.y) +
                       fabsf(d1 - r.z) + fabsf(d2 - r.w);
            pm = fminf(pm, al);
        }
        pm = waveMinF(pm);
        if (lane == 0) {
            mOut[pBase + w] = sVal[w] ? pm : BIGF;
            vOut[pBase + w] = sVal[w];
        }
    }
}

// ---------------- kernel 3: cummin + masked sum (single block) ----------------
__global__ __launch_bounds__(1024) void scan_kernel(const float* __restrict__ m,
                                                    const int*   __restrict__ valid,
                                                    float* __restrict__ out) {
    __shared__ float wAgg[16];
    __shared__ float wSum[16];
    int t = threadIdx.x;
    int lane = t & 63, wid = t >> 6;

    float v[4]; int vl[4];
    #pragma unroll
    for (int j = 0; j < 4; j++) { v[j] = m[4 * t + j]; vl[j] = valid[4 * t + j]; }
    float cmin = fminf(fminf(v[0], v[1]), fminf(v[2], v[3]));

    float inc = cmin;
    #pragma unroll
    for (int o = 1; o < 64; o <<= 1) {
        float u = __shfl_up(inc, o, 64);
        if (lane >= o) inc = fminf(inc, u);
    }
    if (lane == 63) wAgg[wid] = inc;
    __syncthreads();

    float wavePrefix = INFINITY;
    for (int i = 0; i < wid; i++) wavePrefix = fminf(wavePrefix, wAgg[i]);
    float excl = __shfl_up(inc, 1, 64);
    if (lane == 0) excl = INFINITY;
    float run = fminf(wavePrefix, excl);

    float sum = 0.0f;
    #pragma unroll
    for (int j = 0; j < 4; j++) {
        run = fminf(run, v[j]);
        if (vl[j]) sum += run;
    }
    #pragma unroll
    for (int o = 32; o; o >>= 1) sum += __shfl_xor(sum, o, 64);
    if (lane == 0) wSum[wid] = sum;
    __syncthreads();
    if (t == 0) {
        float s = 0.0f;
        for (int i = 0; i < 16; i++) s += wSum[i];
        out[0] = s;
    }
}

extern "C" void kernel_launch(void* const* d_in, const int* in_sizes, int n_in,
                              void* d_out, int out_size, void* d_ws, size_t ws_size,
                              hipStream_t stream) {
    const float* verts   = (const float*)d_in[0];
    const float* tab     = (const float*)d_in[1];
    const int*   edges   = (const int*)d_in[2];
    const int*   listAll = (const int*)d_in[3];

    char* ws = (char*)d_ws;
    float4* pk4 = (float4*)ws;                    ws += NE * sizeof(float4);
    float4* tb4 = (float4*)ws;                    ws += NT * sizeof(float4);
    float2* pk2 = (float2*)ws;                    ws += NE * sizeof(float2);
    float*  ea  = (float*)ws;                     ws += NE * sizeof(float);
    float*  eb  = (float*)ws;                     ws += NE * sizeof(float);
    float*  mArr= (float*)ws;                     ws += NP * sizeof(float);
    int*    vArr= (int*)ws;

    prep_kernel<<<(NE + 255) / 256, 256, 0, stream>>>(verts, edges, tab,
                                                      ea, eb, pk2, pk4, tb4);
    point_kernel<<<NP / NPB, 1024, 0, stream>>>(verts, listAll,
                                                ea, eb, pk2, pk4, tb4,
                                                mArr, vArr);
    scan_kernel<<<1, 1024, 0, stream>>>(mArr, vArr, (float*)d_out);
}

// Round 8
// 27.310 us; speedup vs baseline: 7.1883x; 1.0754x over previous
//
#include <hip/hip_runtime.h>
#include <math.h>

#define NV 65536
#define NE 4096
#define NP 4096
#define NT 512
#define SENTF 1000000000.0f
#define BIGF 1e30f

// ---------------- wave(64) reduction helpers ----------------
__device__ __forceinline__ float waveMinF(float v) {
    #pragma unroll
    for (int o = 32; o; o >>= 1) v = fminf(v, __shfl_xor(v, o, 64));
    return v;
}
__device__ __forceinline__ float waveMaxF(float v) {
    #pragma unroll
    for (int o = 32; o; o >>= 1) v = fmaxf(v, __shfl_xor(v, o, 64));
    return v;
}
__device__ __forceinline__ int waveSumI(int v) {
    #pragma unroll
    for (int o = 32; o; o >>= 1) v += __shfl_xor(v, o, 64);
    return v;
}
__device__ __forceinline__ int waveMinI(int v) {
    #pragma unroll
    for (int o = 32; o; o >>= 1) v = min(v, __shfl_xor(v, o, 64));
    return v;
}

// ---------------- kernel 1: per-edge params + table repack (validated) ----------------
__global__ void prep_kernel(const float* __restrict__ verts,
                            const int*   __restrict__ edges,
                            const float* __restrict__ tab,
                            float*  __restrict__ ea,  float*  __restrict__ eb,
                            float2* __restrict__ pk2, float4* __restrict__ pk4,
                            float4* __restrict__ tb4) {
    int e = blockIdx.x * blockDim.x + threadIdx.x;
    if (e < NT) {
        const float* r = tab + 7 * e;
        tb4[e] = make_float4(r[3], r[4], r[5], r[6]);
    }
    if (e >= NE) return;
    int i0 = edges[2 * e + 0];
    int i1 = edges[2 * e + 1];
    float x0 = verts[3 * i0 + 0], y0 = verts[3 * i0 + 1];
    float x1 = verts[3 * i1 + 0], y1 = verts[3 * i1 + 1];
    float a = (y0 - y1) / (x0 - x1);
    float b = y0 - a * x0;
    ea[e] = a; eb[e] = b;
    pk2[e] = make_float2(fminf(x0, x1), fmaxf(x0, x1));
    pk4[e] = make_float4(fminf(y0, y1), fmaxf(y0, y1), 1.0f / a, b);  // reciprocal hoisted
}

// ---------------- kernel 2: 4 points/block, register-reuse phase 2 ----------------
// 1024 blocks x 256 thr = 4 waves. Wave w: phase-1 for point w; phase-2 covers
// edge quarter [w*1024,(w+1)*1024) for ALL 4 points (each pk4 load reused x4).
__global__ __launch_bounds__(256) void point_kernel(
        const float*  __restrict__ verts,
        const int*    __restrict__ listAll,
        const float*  __restrict__ ea,  const float*  __restrict__ eb,
        const float2* __restrict__ pk2, const float4* __restrict__ pk4,
        const float4* __restrict__ tb4,
        float* __restrict__ mOut, int* __restrict__ vOut) {
    __shared__ float sCY[4], sPX[4], sL1[4], sL2[4];
    __shared__ float sQ[4][4][6];   // [wave][point][stat]
    __shared__ float sF[4][6];      // folded per point
    __shared__ int   sVal[4];

    const int tid  = threadIdx.x;
    const int lane = tid & 63;
    const int w    = tid >> 6;       // 0..3
    const int pBase = blockIdx.x * 4;

    // ---- phase 1: wave w -> point pBase+w (validated early-exit search) ----
    {
        int p  = pBase + w;
        int vi = listAll[p];
        float px = verts[3 * vi + 0];
        float py = verts[3 * vi + 1];
        int minIdx = NE;
        for (int it = 0; it < NE / 64; ++it) {
            int e = it * 64 + lane;
            float2 q = pk2[e];
            bool hit = (px > q.x) && (px < q.y);
            if (hit) minIdx = e;
            if (__any(hit)) break;
        }
        minIdx = waveMinI(minIdx);
        int idx = (minIdx >= NE) ? (NE - 1) : minIdx;
        float exposeY = ea[idx] * px + eb[idx];
        if (lane == 0) {
            sCY[w] = 0.5f * (py + exposeY);
            sL1[w] = fabsf(py - exposeY);
            sPX[w] = px;
        }
    }
    __syncthreads();

    float cyv[4], cxv[4];
    #pragma unroll
    for (int p = 0; p < 4; ++p) { cyv[p] = sCY[p]; cxv[p] = sPX[p]; }

    // ---- phase 2: per-point accumulators, each edge load reused x4 ----
    float mx[4], mn[4], xs[4], xf[4];
    int   nC[4], hh[4];               // hh = hasS | hasI<<16
    #pragma unroll
    for (int p = 0; p < 4; ++p) {
        mx[p] = -SENTF; mn[p] = SENTF; xs[p] = SENTF; xf[p] = -SENTF;
        nC[p] = 0; hh[p] = 0;
    }

    #pragma unroll 4
    for (int it = 0; it < 16; ++it) {
        float4 q = pk4[w * 1024 + it * 64 + lane];   // (ymn, ymx, 1/a, b)
        #pragma unroll
        for (int p = 0; p < 4; ++p) {
            float cy = cyv[p], cx = cxv[p];
            bool  c  = (cy > q.x) && (cy < q.y);
            float xi = (cy - q.w) * q.z;             // identical arithmetic to validated path
            nC[p] += c ? 1 : 0;
            mx[p] = fmaxf(mx[p], c ? xi : -SENTF);
            mn[p] = fminf(mn[p], c ? xi :  SENTF);
            bool sp  = c && (xi >= cx);
            bool in_ = c && (xi <  cx);
            xs[p] = fminf(xs[p], sp  ? xi :  SENTF);
            xf[p] = fmaxf(xf[p], in_ ? xi : -SENTF);
            hh[p] |= (sp ? 1 : 0) | (in_ ? 0x10000 : 0);
        }
    }

    // ---- wave-reduce each point's stats, lane0 -> LDS ----
    #pragma unroll
    for (int p = 0; p < 4; ++p) {
        float a0 = waveMaxF(mx[p]);
        float a1 = waveMinF(mn[p]);
        float a2 = waveMinF(xs[p]);
        float a3 = waveMaxF(xf[p]);
        int   a4 = waveSumI(nC[p]);
        int   a5 = waveSumI(hh[p]);   // fields <= 64 each, no carry
        if (lane == 0) {
            sQ[w][p][0] = a0; sQ[w][p][1] = a1;
            sQ[w][p][2] = a2; sQ[w][p][3] = a3;
            sQ[w][p][4] = __int_as_float(a4);
            sQ[w][p][5] = __int_as_float(a5);
        }
    }
    __syncthreads();

    // ---- fold 4 waves: 24 threads, one (point, stat) each ----
    if (tid < 24) {
        int p = tid & 3, s = tid >> 2;   // s in 0..5
        if (s == 0)      sF[p][0] = fmaxf(fmaxf(sQ[0][p][0], sQ[1][p][0]), fmaxf(sQ[2][p][0], sQ[3][p][0]));
        else if (s == 1) sF[p][1] = fminf(fminf(sQ[0][p][1], sQ[1][p][1]), fminf(sQ[2][p][1], sQ[3][p][1]));
        else if (s == 2) sF[p][2] = fminf(fminf(sQ[0][p][2], sQ[1][p][2]), fminf(sQ[2][p][2], sQ[3][p][2]));
        else if (s == 3) sF[p][3] = fmaxf(fmaxf(sQ[0][p][3], sQ[1][p][3]), fmaxf(sQ[2][p][3], sQ[3][p][3]));
        else if (s == 4) sF[p][4] = __int_as_float(__float_as_int(sQ[0][p][4]) + __float_as_int(sQ[1][p][4])
                                                 + __float_as_int(sQ[2][p][4]) + __float_as_int(sQ[3][p][4]));
        else             sF[p][5] = __int_as_float(__float_as_int(sQ[0][p][5]) + __float_as_int(sQ[1][p][5])
                                                 + __float_as_int(sQ[2][p][5]) + __float_as_int(sQ[3][p][5]));
    }
    __syncthreads();

    // ---- per-point finish: valid, L2 ----
    if (tid < 4) {
        int n  = __float_as_int(sF[tid][4]);
        int hc = __float_as_int(sF[tid][5]);
        int hS = hc & 0xFFFF, hI = hc >> 16;
        bool valid = (n == 2) || ((n > 2) && (hS > 0) && (hI > 0));
        float dx = (n == 2) ? (sF[tid][0] - sF[tid][1]) : (sF[tid][2] - sF[tid][3]);
        sL2[tid]  = fabsf(dx);
        sVal[tid] = valid ? 1 : 0;
    }
    __syncthreads();

    // ---- table min: wave w -> point w (validated float4 path) ----
    {
        float L1v = sL1[w], L2v = sL2[w];
        float d1  = fabsf(sCY[w] - 1.0f);
        float d2  = fabsf(sPX[w] - 1.0f);
        float pm = INFINITY;
        #pragma unroll
        for (int kk = 0; kk < NT / 64; ++kk) {
            float4 r = tb4[kk * 64 + lane];
            float al = fabsf(L1v - r.x) + fabsf(L2v - r.y) +
                       fabsf(d1 - r.z) + fabsf(d2 - r.w);
            pm = fminf(pm, al);
        }
        pm = waveMinF(pm);
        if (lane == 0) {
            mOut[pBase + w] = sVal[w] ? pm : BIGF;
            vOut[pBase + w] = sVal[w];
        }
    }
}

// ---------------- kernel 3: cummin + masked sum (validated) ----------------
__global__ __launch_bounds__(1024) void scan_kernel(const float* __restrict__ m,
                                                    const int*   __restrict__ valid,
                                                    float* __restrict__ out) {
    __shared__ float wAgg[16];
    __shared__ float wSum[16];
    int t = threadIdx.x;
    int lane = t & 63, wid = t >> 6;

    float v[4]; int vl[4];
    #pragma unroll
    for (int j = 0; j < 4; j++) { v[j] = m[4 * t + j]; vl[j] = valid[4 * t + j]; }
    float cmin = fminf(fminf(v[0], v[1]), fminf(v[2], v[3]));

    float inc = cmin;
    #pragma unroll
    for (int o = 1; o < 64; o <<= 1) {
        float u = __shfl_up(inc, o, 64);
        if (lane >= o) inc = fminf(inc, u);
    }
    if (lane == 63) wAgg[wid] = inc;
    __syncthreads();

    float wavePrefix = INFINITY;
    for (int i = 0; i < wid; i++) wavePrefix = fminf(wavePrefix, wAgg[i]);
    float excl = __shfl_up(inc, 1, 64);
    if (lane == 0) excl = INFINITY;
    float run = fminf(wavePrefix, excl);

    float sum = 0.0f;
    #pragma unroll
    for (int j = 0; j < 4; j++) {
        run = fminf(run, v[j]);
        if (vl[j]) sum += run;
    }
    #pragma unroll
    for (int o = 32; o; o >>= 1) sum += __shfl_xor(sum, o, 64);
    if (lane == 0) wSum[wid] = sum;
    __syncthreads();
    if (t == 0) {
        float s = 0.0f;
        for (int i = 0; i < 16; i++) s += wSum[i];
        out[0] = s;
    }
}

extern "C" void kernel_launch(void* const* d_in, const int* in_sizes, int n_in,
                              void* d_out, int out_size, void* d_ws, size_t ws_size,
                              hipStream_t stream) {
    const float* verts   = (const float*)d_in[0];
    const float* tab     = (const float*)d_in[1];
    const int*   edges   = (const int*)d_in[2];
    const int*   listAll = (const int*)d_in[3];

    char* ws = (char*)d_ws;
    float4* pk4 = (float4*)ws;                    ws += NE * sizeof(float4);
    float4* tb4 = (float4*)ws;                    ws += NT * sizeof(float4);
    float2* pk2 = (float2*)ws;                    ws += NE * sizeof(float2);
    float*  ea  = (float*)ws;                     ws += NE * sizeof(float);
    float*  eb  = (float*)ws;                     ws += NE * sizeof(float);
    float*  mArr= (float*)ws;                     ws += NP * sizeof(float);
    int*    vArr= (int*)ws;

    prep_kernel<<<(NE + 255) / 256, 256, 0, stream>>>(verts, edges, tab,
                                                      ea, eb, pk2, pk4, tb4);
    point_kernel<<<NP / 4, 256, 0, stream>>>(verts, listAll,
                                             ea, eb, pk2, pk4, tb4,
                                             mArr, vArr);
    scan_kernel<<<1, 1024, 0, stream>>>(mArr, vArr, (float*)d_out);
}